// Round 5
// baseline (285.612 us; speedup 1.0000x reference)
//
#include <hip/hip_runtime.h>
#include <math.h>

// ---------------------------------------------------------------------------
// FraudDetectionGCN: 3x GCNConv(relu) + FC + log_softmax.
// R19 changes vs R18 (251.1 us):
//  * gather_row4 restructured for memory-level parallelism. Old loop issued
//    4 row-loads then consumed them; the per-j0 early-break blocked load
//    hoisting -> <=512B in flight per 16-lane group (latency-bound; R18's
//    epilogue fix exposed this). New: full 16-edge groups run branchless
//    with all 16 shfl+loads issued back-to-back (4x MLP, tree adds, zero
//    waste — all slots valid by construction); <16-edge tail keeps the
//    4-granular early-break (R10/R14 lesson). ~65% of edges hit the bulk
//    path at mean degree 17.
//  * kept: R18 MFMA epilogue + bf16 h staging, R17 lin_mfma + zero-row,
//    R15 1024-thread scatter/hist.
// agg: bf16 g rows; norm factorization:
// out[n] = dinv[n]*(sum_{s->n} g[s] + g[n]) + b, g = dinv[:,None]*(h@W).
// ---------------------------------------------------------------------------

static inline size_t alignup(size_t x){ return (x + 511) & ~size_t(511); }

typedef float v4f __attribute__((ext_vector_type(4)));
typedef unsigned short v4u16 __attribute__((ext_vector_type(4)));
typedef __attribute__((ext_vector_type(8))) short short8;   // MFMA A/B frag (8 bf16)
typedef __attribute__((ext_vector_type(4))) float f32x4;    // MFMA C/D frag

__device__ __forceinline__ unsigned short f32_to_bf16(float f){
  union { float f; unsigned int u; } c; c.f = f;
  unsigned int u = c.u + 0x7FFFu + ((c.u >> 16) & 1u);   // round-nearest-even
  return (unsigned short)(u >> 16);
}
__device__ __forceinline__ v4f bf16x4_to_f32(v4u16 a){
  union { unsigned int u; float f; } c0,c1,c2,c3;
  c0.u = (unsigned int)a.x << 16;
  c1.u = (unsigned int)a.y << 16;
  c2.u = (unsigned int)a.z << 16;
  c3.u = (unsigned int)a.w << 16;
  v4f r; r.x=c0.f; r.y=c1.f; r.z=c2.f; r.w=c3.f;
  return r;
}

#define NBUCK 1024          // histogram bins (dst>>7); 782 used at N=100k
#define CHUNK 8192          // edges per block in hist/scatter (196 blocks)
#define CCAP  3584          // max edges per bucket (mean ~2046, +30 sigma)

__global__ void zero_kernel(int* __restrict__ p, int n){
  int i = blockIdx.x*256 + threadIdx.x;
  if(i<n) p[i] = 0;
}

// Build bf16 MFMA B-fragments for W[ksteps*32][64]:
// wf[ks][nb][lane][i] = bf16( W[ks*32 + 8*(lane>>4) + i][nb*16 + (lane&15)] ).
__global__ void wfrag_kernel(const float* __restrict__ W,
                             unsigned short* __restrict__ wf, int ksteps){
  int t = threadIdx.x + blockIdx.x*256;
  int total = ksteps*4*64;
  if(t >= total) return;
  int l  = t & 63;
  int nb = (t>>6) & 3;
  int ks = t>>8;
  int k0 = ks*32 + 8*(l>>4);
  int n  = nb*16 + (l&15);
  unsigned short* o = wf + (size_t)t*8;
  #pragma unroll
  for(int i=0;i<8;i++) o[i] = f32_to_bf16(W[(size_t)(k0+i)*64 + n]);
}

// Pass A: global histogram of dst>>7 (LDS-aggregated). 1024 thr = 16 waves.
__global__ __launch_bounds__(1024) void hist_kernel(const int* __restrict__ dst,
                                                    int* __restrict__ bcnt, int E){
  __shared__ int h[NBUCK];
  int t = threadIdx.x;
  h[t]=0;                         // NBUCK == blockDim == 1024
  __syncthreads();
  int base = blockIdx.x*CHUNK;
  #pragma unroll
  for(int i=0;i<CHUNK;i+=1024){
    int e = base+i+t;
    if(e<E) atomicAdd(&h[dst[e]>>7], 1);
  }
  __syncthreads();
  if(h[t]) atomicAdd(&bcnt[t], h[t]);
}

// Exclusive scan of 1024 bucket counts (single block). bbase = bfill = prefix.
__global__ void scan_buckets_kernel(const int* __restrict__ bcnt, int* __restrict__ bbase,
                                    int* __restrict__ bfill){
  __shared__ int sh[256];
  int t = threadIdx.x;
  int v0=bcnt[4*t], v1=bcnt[4*t+1], v2=bcnt[4*t+2], v3=bcnt[4*t+3];
  int ts = v0+v1+v2+v3;
  sh[t]=ts; __syncthreads();
  for(int off=1; off<256; off<<=1){
    int x=(t>=off)?sh[t-off]:0; __syncthreads();
    sh[t]+=x; __syncthreads();
  }
  int run = sh[t]-ts;
  int i0=4*t;
  bbase[i0+0]=run; bfill[i0+0]=run; run+=v0;
  bbase[i0+1]=run; bfill[i0+1]=run; run+=v1;
  bbase[i0+2]=run; bfill[i0+2]=run; run+=v2;
  bbase[i0+3]=run; bfill[i0+3]=run;
}

// Pass B: scatter packed (local_dst<<17 | src) into bucket regions,
// LDS-presorted so global writes are dense runs. 1024 threads (16 waves).
__global__ __launch_bounds__(1024) void scatter_kernel(const int* __restrict__ src,
                                                       const int* __restrict__ dst,
                                                       int* __restrict__ bfill,
                                                       int* __restrict__ pairs, int E){
  __shared__ int hist[NBUCK];            // counts -> reused as fill counters
  __shared__ int delta[NBUCK];           // gbase - lstart per bucket
  __shared__ int wsum[16];
  __shared__ int vals[CHUNK];            // 32KB sorted-by-bucket payloads
  __shared__ unsigned short bkt[CHUNK];  // 16KB bucket id per slot
  int t = threadIdx.x;
  int lane = t & 63, wid = t >> 6;
  int cbase = blockIdx.x*CHUNK;
  hist[t]=0;                             // NBUCK == 1024
  __syncthreads();
  // A: local histogram
  #pragma unroll
  for(int i=0;i<CHUNK;i+=1024){
    int e = cbase+i+t;
    if(e<E) atomicAdd(&hist[dst[e]>>7], 1);
  }
  __syncthreads();
  // B: block-exclusive scan (1 bucket/thread): wave shfl scan + combine
  int v = hist[t];
  int x = v;
  #pragma unroll
  for(int off=1; off<64; off<<=1){
    int y = __shfl_up(x, off, 64);
    if(lane >= off) x += y;
  }
  if(lane==63) wsum[wid]=x;
  __syncthreads();
  if(wid==0){
    int s2 = (lane<16) ? wsum[lane] : 0;
    #pragma unroll
    for(int off=1; off<16; off<<=1){
      int y = __shfl_up(s2, off, 64);
      if(lane >= off) s2 += y;
    }
    if(lane<16) wsum[lane]=s2;
  }
  __syncthreads();
  int run = (x - v) + (wid ? wsum[wid-1] : 0);      // exclusive local start
  int g = v ? atomicAdd(&bfill[t], v) : 0;          // global base reservation
  hist[t]=run; delta[t]=g-run;                      // hist becomes fill counter
  __syncthreads();
  // C: place into LDS sorted by bucket
  #pragma unroll
  for(int i=0;i<CHUNK;i+=1024){
    int e = cbase+i+t;
    if(e<E){
      int d = dst[e];
      int b = d>>7;
      int slot = atomicAdd(&hist[b], 1);
      vals[slot] = ((d&127)<<17) | src[e];
      bkt[slot]  = (unsigned short)b;
    }
  }
  __syncthreads();
  // D: dense copy-out (addresses consecutive within each run)
  int cnt = E - cbase; if(cnt > CHUNK) cnt = CHUNK;
  for(int i=t;i<cnt;i+=1024){
    int b = bkt[i];
    pairs[delta[b] + i] = vals[i];
  }
}

// Pass C: one block per bucket (128 dst nodes). LDS counting sort ->
// row_ptr, dinv, srcs staged in LDS -> fully-contiguous col writes.
__global__ __launch_bounds__(256) void bucket_csr_kernel(const int* __restrict__ pairs,
                                                         const int* __restrict__ bbase,
                                                         int* __restrict__ row_ptr,
                                                         float* __restrict__ dinv,
                                                         int* __restrict__ col,
                                                         int N, int E){
  __shared__ int hist[128];
  __shared__ int pref[128];
  __shared__ int fill[128];
  __shared__ int srcs[CCAP];
  int b = blockIdx.x, t = threadIdx.x;
  int s = bbase[b], e = bbase[b+1];
  int cnt = e - s; if(cnt > CCAP) cnt = CCAP;   // unreachable guard
  if(t<128) hist[t]=0;
  __syncthreads();
  int v[CCAP/256];
  #pragma unroll
  for(int i=0;i<CCAP/256;i++){
    int idx = i*256 + t;
    if(idx<cnt){ v[i]=pairs[s+idx]; atomicAdd(&hist[v[i]>>17], 1); }
  }
  __syncthreads();
  if(t<128) pref[t]=hist[t];
  __syncthreads();
  for(int off=1; off<128; off<<=1){
    int x=0;
    if(t<128 && t>=off) x=pref[t-off];
    __syncthreads();
    if(t<128) pref[t]+=x;
    __syncthreads();
  }
  if(t<128){
    int ex = pref[t]-hist[t];                 // exclusive prefix
    fill[t]=ex;
    int node = b*128 + t;
    if(node<N){
      row_ptr[node] = s + ex;
      dinv[node] = rsqrtf((float)(hist[t]+1)); // +1 self loop
    }
  }
  if(b==0 && t==0) row_ptr[N]=E;
  __syncthreads();
  #pragma unroll
  for(int i=0;i<CCAP/256;i++){
    int idx = i*256 + t;
    if(idx<cnt){
      int ld = v[i]>>17;
      int pos = atomicAdd(&fill[ld], 1);
      srcs[pos] = v[i] & 0x1FFFF;
    }
  }
  __syncthreads();
  for(int i=t;i<cnt;i+=256) col[s+i]=srcs[i];   // contiguous
}

// g[n,:] = bf16( dinv[n] * (x[n,:128] @ W1[128,64]) ) via MFMA 16x16x32 bf16.
// Block = 64 rows (4 waves x 16 rows), 16 MFMAs/wave (4 ksteps x 4 nblocks).
// A-frags from global (lane l: row l&15, k-octet 8*(l>>4)); B-frags from LDS.
__global__ __launch_bounds__(256) void lin_mfma_kernel(const float* __restrict__ x,
                                                       const unsigned short* __restrict__ wf,
                                                       const float* __restrict__ dinv,
                                                       unsigned short* __restrict__ g,
                                                       int N){
  __shared__ __align__(16) unsigned short wl[4*4*64*8];   // 16KB
  int t = threadIdx.x, wave = t>>6, lane = t&63;
  #pragma unroll
  for(int idx=t; idx<1024; idx+=256)
    ((v4f*)wl)[idx] = ((const v4f*)wf)[idx];              // 16B per entry
  __syncthreads();
  int row = blockIdx.x*64 + wave*16 + (lane&15);
  int arow = row < N ? row : N-1;
  const float* xr = x + (size_t)arow*128 + 8*(lane>>4);
  f32x4 acc0={0.f,0.f,0.f,0.f}, acc1=acc0, acc2=acc0, acc3=acc0;
  #pragma unroll
  for(int ks=0; ks<4; ks++){
    v4f a0 = *(const v4f*)(xr + ks*32);
    v4f a1 = *(const v4f*)(xr + ks*32 + 4);
    short8 af;
    af[0]=(short)f32_to_bf16(a0.x); af[1]=(short)f32_to_bf16(a0.y);
    af[2]=(short)f32_to_bf16(a0.z); af[3]=(short)f32_to_bf16(a0.w);
    af[4]=(short)f32_to_bf16(a1.x); af[5]=(short)f32_to_bf16(a1.y);
    af[6]=(short)f32_to_bf16(a1.z); af[7]=(short)f32_to_bf16(a1.w);
    const short8* wb = ((const short8*)wl) + ks*256 + lane;
    acc0 = __builtin_amdgcn_mfma_f32_16x16x32_bf16(af, wb[0],   acc0, 0, 0, 0);
    acc1 = __builtin_amdgcn_mfma_f32_16x16x32_bf16(af, wb[64],  acc1, 0, 0, 0);
    acc2 = __builtin_amdgcn_mfma_f32_16x16x32_bf16(af, wb[128], acc2, 0, 0, 0);
    acc3 = __builtin_amdgcn_mfma_f32_16x16x32_bf16(af, wb[192], acc3, 0, 0, 0);
  }
  // C layout (m89-verified): col = lane&15, row = (lane>>4)*4 + j.
  int rbase = blockIdx.x*64 + wave*16 + (lane>>4)*4;
  int c = lane & 15;
  #pragma unroll
  for(int j=0;j<4;j++){
    int r = rbase + j;
    if(r < N){
      float dv = dinv[r];
      unsigned short* go = g + (size_t)r*64 + c;
      go[0]  = f32_to_bf16(dv*acc0[j]);
      go[16] = f32_to_bf16(dv*acc1[j]);
      go[32] = f32_to_bf16(dv*acc2[j]);
      go[48] = f32_to_bf16(dv*acc3[j]);
    }
  }
}

// Gather for 4-nodes-per-wave layout over bf16 g rows (128B each):
// lane = 16*q + l; group q handles node n, lane carries features [4l,4l+4).
// Bulk: full 16-edge groups, branchless, all 16 loads in flight (4x MLP).
// Tail (<16): 4-granular early break, OOB slots clamp to zeroed row g[ZR].
__device__ __forceinline__ v4f gather_row4(const unsigned short* __restrict__ g,
                                           const int* __restrict__ col,
                                           int n, int s, int e, int l, int ZR){
  v4f acc = bf16x4_to_f32(*(const v4u16*)&g[(size_t)n*64 + l*4]);   // self
  int full = s + ((e - s) & ~15);
  for(int i = s; i < full; i += 16){
    int myc = col[i + l];                          // all 16 valid
    v4u16 r[16];
    #pragma unroll
    for(int j=0;j<16;j++){
      int c = __shfl(myc, j, 16);
      r[j] = *(const v4u16*)&g[(size_t)c*64 + l*4];
    }
    v4f s0 = (bf16x4_to_f32(r[0])  + bf16x4_to_f32(r[1]))
           + (bf16x4_to_f32(r[2])  + bf16x4_to_f32(r[3]));
    v4f s1 = (bf16x4_to_f32(r[4])  + bf16x4_to_f32(r[5]))
           + (bf16x4_to_f32(r[6])  + bf16x4_to_f32(r[7]));
    v4f s2 = (bf16x4_to_f32(r[8])  + bf16x4_to_f32(r[9]))
           + (bf16x4_to_f32(r[10]) + bf16x4_to_f32(r[11]));
    v4f s3 = (bf16x4_to_f32(r[12]) + bf16x4_to_f32(r[13]))
           + (bf16x4_to_f32(r[14]) + bf16x4_to_f32(r[15]));
    acc = acc + ((s0 + s1) + (s2 + s3));
  }
  if(full < e){
    int rem = e - full;                            // 1..15, group-uniform
    int myc = (l < rem) ? col[full + l] : ZR;
    #pragma unroll
    for(int j0 = 0; j0 < 16; j0 += 4){
      int c0 = __shfl(myc, j0+0, 16);
      int c1 = __shfl(myc, j0+1, 16);
      int c2 = __shfl(myc, j0+2, 16);
      int c3 = __shfl(myc, j0+3, 16);
      v4f x0 = bf16x4_to_f32(*(const v4u16*)&g[(size_t)c0*64 + l*4]);
      v4f x1 = bf16x4_to_f32(*(const v4u16*)&g[(size_t)c1*64 + l*4]);
      v4f x2 = bf16x4_to_f32(*(const v4u16*)&g[(size_t)c2*64 + l*4]);
      v4f x3 = bf16x4_to_f32(*(const v4u16*)&g[(size_t)c3*64 + l*4]);
      acc = acc + ((x0 + x1) + (x2 + x3));         // pk_add; same association
      if(j0+4 >= rem) break;                       // group-uniform early out
    }
  }
  return acc;
}

// Fused agg + next-layer linear. h = relu(dinv*gather + b) -> bf16 rows in
// LDS (144B pitch), then h[16x64] @ W[64x64] via 8 MFMAs (2/wave):
// wave = output col-block nb; A-frag: lane l reads row l&15, k-octet
// 8*(l>>4) (ds_read_b128, 16B-aligned, bank-stride 4 -> 2-way free).
__global__ __launch_bounds__(256) void agg_lin_kernel(const unsigned short* __restrict__ g,
                                                      const int* __restrict__ row_ptr,
                                                      const int* __restrict__ col,
                                                      const float* __restrict__ dinv,
                                                      const float* __restrict__ bias,
                                                      const unsigned short* __restrict__ wf,
                                                      unsigned short* __restrict__ g2,
                                                      int N){
  __shared__ __align__(16) unsigned short hsh[16*72];     // 2.25KB padded bf16 h
  __shared__ __align__(16) unsigned short wl[2*4*64*8];   // 8KB W frags
  int t = threadIdx.x, wave = t>>6, lane = t&63;
  int l = lane & 15, q = lane >> 4;
  // stage W frags once per block: 512 x 16B, coalesced
  #pragma unroll
  for(int idx = t; idx < 512; idx += 256)
    ((v4f*)wl)[idx] = ((const v4f*)wf)[idx];
  int base = blockIdx.x*16;
  int n = base + wave*4 + q;
  bool valid = n < N;
  int nn = valid ? n : (N-1);
  int s = row_ptr[nn], e = row_ptr[nn+1];
  v4f acc = gather_row4(g, col, nn, s, e, l, N);
  float dv = dinv[nn];
  v4f bs = *(const v4f*)&bias[l*4];
  v4u16 hb;
  hb.x = f32_to_bf16(fmaxf(fmaf(dv, acc.x, bs.x), 0.f));
  hb.y = f32_to_bf16(fmaxf(fmaf(dv, acc.y, bs.y), 0.f));
  hb.z = f32_to_bf16(fmaxf(fmaf(dv, acc.z, bs.z), 0.f));
  hb.w = f32_to_bf16(fmaxf(fmaf(dv, acc.w, bs.w), 0.f));
  *(v4u16*)&hsh[(wave*4+q)*72 + l*4] = hb;
  __syncthreads();
  // ---- h @ W via MFMA; this wave handles col-block nb = wave ----
  short8 a0 = *(const short8*)&hsh[(lane&15)*72 +      8*(lane>>4)];
  short8 a1 = *(const short8*)&hsh[(lane&15)*72 + 32 + 8*(lane>>4)];
  const short8* wb = ((const short8*)wl) + wave*64 + lane;
  f32x4 oc = {0.f,0.f,0.f,0.f};
  oc = __builtin_amdgcn_mfma_f32_16x16x32_bf16(a0, wb[0],   oc, 0, 0, 0);
  oc = __builtin_amdgcn_mfma_f32_16x16x32_bf16(a1, wb[256], oc, 0, 0, 0);
  // C layout: col = lane&15, row = (lane>>4)*4 + j
  int c  = wave*16 + (lane&15);
  int r0 = base + (lane>>4)*4;
  #pragma unroll
  for(int j=0;j<4;j++){
    int r = r0 + j;
    if(r < N)
      g2[(size_t)r*64 + c] = f32_to_bf16(dinv[r]*oc[j]);
  }
}

// Layer-3 agg with fused FC + log_softmax epilogue: never materializes h3.
__global__ __launch_bounds__(256) void agg_final_kernel(const unsigned short* __restrict__ g,
                                                        const int* __restrict__ row_ptr,
                                                        const int* __restrict__ col,
                                                        const float* __restrict__ dinv,
                                                        const float* __restrict__ bias,
                                                        const float* __restrict__ Wfc,
                                                        const float* __restrict__ bfc,
                                                        float* __restrict__ out, int N){
  int t = threadIdx.x, wave = t>>6, lane = t&63;
  int l = lane & 15, q = lane >> 4;
  int n = blockIdx.x*16 + wave*4 + q;
  bool valid = n < N;
  if(!valid) n = N-1;
  int s = row_ptr[n], e = row_ptr[n+1];
  v4f acc = gather_row4(g, col, n, s, e, l, N);
  float dv = dinv[n];
  v4f bs = *(const v4f*)&bias[l*4];
  v4f hv;
  hv.x = fmaxf(fmaf(dv, acc.x, bs.x), 0.f);
  hv.y = fmaxf(fmaf(dv, acc.y, bs.y), 0.f);
  hv.z = fmaxf(fmaf(dv, acc.z, bs.z), 0.f);
  hv.w = fmaxf(fmaf(dv, acc.w, bs.w), 0.f);
  // Wfc row-major [64][2]: lane l covers features 4l..4l+3 -> 8 floats at 8l.
  v4f wa = *(const v4f*)&Wfc[l*8];
  v4f wb = *(const v4f*)&Wfc[l*8+4];
  float p0 = hv.x*wa.x + hv.y*wa.z + hv.z*wb.x + hv.w*wb.z;
  float p1 = hv.x*wa.y + hv.y*wa.w + hv.z*wb.y + hv.w*wb.w;
  for(int off=8; off; off>>=1){
    p0 += __shfl_down(p0, off, 16);
    p1 += __shfl_down(p1, off, 16);
  }
  if(valid && l==0){
    float l0 = p0 + bfc[0], l1 = p1 + bfc[1];
    float m  = fmaxf(l0, l1);
    float lse = m + logf(expf(l0-m) + expf(l1-m));
    out[(size_t)n*2+0] = l0 - lse;
    out[(size_t)n*2+1] = l1 - lse;
  }
}

extern "C" void kernel_launch(void* const* d_in, const int* in_sizes, int n_in,
                              void* d_out, int out_size, void* d_ws, size_t ws_size,
                              hipStream_t stream) {
  (void)n_in; (void)out_size; (void)ws_size;
  const float* x   = (const float*)d_in[0];
  const int*   ei  = (const int*)  d_in[1];
  const float* W1  = (const float*)d_in[2];
  const float* b1  = (const float*)d_in[3];
  const float* W2  = (const float*)d_in[4];
  const float* b2  = (const float*)d_in[5];
  const float* W3  = (const float*)d_in[6];
  const float* b3  = (const float*)d_in[7];
  const float* Wfc = (const float*)d_in[8];
  const float* bfc = (const float*)d_in[9];
  float* out = (float*)d_out;

  const int N = in_sizes[0] / 128;   // 100000
  const int E = in_sizes[1] / 2;     // 1600000
  const int* src = ei;
  const int* dst = ei + E;
  const int NB = (N + 127) / 128;    // 782 buckets

  // ---- workspace carve ----
  char* w = (char*)d_ws;
  int*   bcnt    = (int*)  w; w += alignup((size_t)NBUCK*4);
  int*   bbase   = (int*)  w; w += alignup((size_t)(NBUCK+1)*4);
  int*   bfill   = (int*)  w; w += alignup((size_t)NBUCK*4);
  int*   pairs   = (int*)  w; w += alignup((size_t)E*4);
  int*   row_ptr = (int*)  w; w += alignup((size_t)(N+1)*4);
  float* dinv    = (float*)w; w += alignup((size_t)N*4);
  int*   col     = (int*)  w; w += alignup((size_t)E*4);
  unsigned short* gA = (unsigned short*)w; w += alignup((size_t)(N+1)*64*2); // bf16 (+zero row)
  unsigned short* gB = (unsigned short*)w; w += alignup((size_t)(N+1)*64*2); // bf16 (+zero row)
  unsigned short* wf1 = (unsigned short*)w; w += alignup((size_t)4*4*64*8*2); // W1 frags 16KB
  unsigned short* wf2 = (unsigned short*)w; w += alignup((size_t)2*4*64*8*2); // W2 frags 8KB
  unsigned short* wf3 = (unsigned short*)w; w += alignup((size_t)2*4*64*8*2); // W3 frags 8KB

  const int nblkE   = (E + CHUNK - 1) / CHUNK;   // 196
  const int nblkLin = (N + 63) / 64;             // 64 rows per MFMA block
  const int nblkAgg = (N + 15) / 16;             // 4 nodes/wave, 4 waves/blk

  // ---- setup: zero counters + zero rows; W fragment builds ----
  zero_kernel<<<(NBUCK+255)/256, 256, 0, stream>>>(bcnt, NBUCK);
  zero_kernel<<<1, 256, 0, stream>>>((int*)(gA + (size_t)N*64), 32);
  zero_kernel<<<1, 256, 0, stream>>>((int*)(gB + (size_t)N*64), 32);
  wfrag_kernel<<<4, 256, 0, stream>>>(W1, wf1, 4);
  wfrag_kernel<<<2, 256, 0, stream>>>(W2, wf2, 2);
  wfrag_kernel<<<2, 256, 0, stream>>>(W3, wf3, 2);

  // ---- CSR build ----
  hist_kernel<<<nblkE, 1024, 0, stream>>>(dst, bcnt, E);
  scan_buckets_kernel<<<1, 256, 0, stream>>>(bcnt, bbase, bfill);
  scatter_kernel<<<nblkE, 1024, 0, stream>>>(src, dst, bfill, pairs, E);
  bucket_csr_kernel<<<NB, 256, 0, stream>>>(pairs, bbase, row_ptr, dinv, col, N, E);

  // ---- layer 1 linear via MFMA: x[N,128] -> gA ----
  lin_mfma_kernel<<<nblkLin, 256, 0, stream>>>(x, wf1, dinv, gA, N);
  // ---- agg1 + lin2 fused (MFMA epilogue): gA -> gB ----
  agg_lin_kernel<<<nblkAgg, 256, 0, stream>>>(gA, row_ptr, col, dinv, b1, wf2, gB, N);
  // ---- agg2 + lin3 fused (MFMA epilogue): gB -> gA ----
  agg_lin_kernel<<<nblkAgg, 256, 0, stream>>>(gB, row_ptr, col, dinv, b2, wf3, gA, N);
  // ---- agg3 + FC + log_softmax (fused): gA -> out ----
  agg_final_kernel<<<nblkAgg, 256, 0, stream>>>(gA, row_ptr, col, dinv, b3,
                                                Wfc, bfc, out, N);
}

// Round 6
// 233.553 us; speedup vs baseline: 1.2229x; 1.2229x over previous
//
#include <hip/hip_runtime.h>
#include <math.h>

// ---------------------------------------------------------------------------
// FraudDetectionGCN: 3x GCNConv(relu) + FC + log_softmax.
// R20 changes vs R19 (285.6 us, regression) / R18 (251.1 us):
//  * gather_row4 reverted to R18's 4-granular early-break form. R19's
//    16-deep bulk batch regressed (occupancy 67->36, VALUBusy 57->29):
//    single drain point = max-of-16 latency with no consume overlap;
//    4-granular batches overlap consume with next batch's latency.
//  * CSR build: hist + scan + bcnt-zero DELETED. Buckets get fixed-stride
//    regions (b*CCAP; CCAP = mean+34sigma, overflow P ~ 1e-200). scatter
//    reserves directly from zeroed bfill; pairs/col are bucket-strided.
//    row_ptr -> int2 rowse[N] {start,end} (one 8B load in gather vs two).
//    Launches 11 -> 7 (one setup kernel: 3x wfrag + bfill/zero-row init).
//  * kept: R18 MFMA epilogue + bf16 h staging, R17 lin_mfma + zero-row,
//    R15 1024-thread scatter.
// agg: bf16 g rows; norm factorization:
// out[n] = dinv[n]*(sum_{s->n} g[s] + g[n]) + b, g = dinv[:,None]*(h@W).
// ---------------------------------------------------------------------------

static inline size_t alignup(size_t x){ return (x + 511) & ~size_t(511); }

typedef float v4f __attribute__((ext_vector_type(4)));
typedef unsigned short v4u16 __attribute__((ext_vector_type(4)));
typedef __attribute__((ext_vector_type(8))) short short8;   // MFMA A/B frag (8 bf16)
typedef __attribute__((ext_vector_type(4))) float f32x4;    // MFMA C/D frag

__device__ __forceinline__ unsigned short f32_to_bf16(float f){
  union { float f; unsigned int u; } c; c.f = f;
  unsigned int u = c.u + 0x7FFFu + ((c.u >> 16) & 1u);   // round-nearest-even
  return (unsigned short)(u >> 16);
}
__device__ __forceinline__ v4f bf16x4_to_f32(v4u16 a){
  union { unsigned int u; float f; } c0,c1,c2,c3;
  c0.u = (unsigned int)a.x << 16;
  c1.u = (unsigned int)a.y << 16;
  c2.u = (unsigned int)a.z << 16;
  c3.u = (unsigned int)a.w << 16;
  v4f r; r.x=c0.f; r.y=c1.f; r.z=c2.f; r.w=c3.f;
  return r;
}

#define NBUCK 1024          // histogram bins (dst>>7); 782 used at N=100k
#define CHUNK 8192          // edges per block in scatter (196 blocks)
#define CCAP  3584          // bucket region stride (mean ~2046, +34 sigma)

// Build one bf16 MFMA B-fragment entry for W[ksteps*32][64]:
// wf[ks][nb][lane][i] = bf16( W[ks*32 + 8*(lane>>4) + i][nb*16 + (lane&15)] ).
__device__ __forceinline__ void wfrag_one(const float* __restrict__ W,
                                          unsigned short* __restrict__ wf,
                                          int idx, int ksteps){
  int total = ksteps*4*64;
  if(idx >= total) return;
  int l  = idx & 63;
  int nb = (idx>>6) & 3;
  int ks = idx>>8;
  int k0 = ks*32 + 8*(l>>4);
  int n  = nb*16 + (l&15);
  unsigned short* o = wf + (size_t)idx*8;
  #pragma unroll
  for(int i=0;i<8;i++) o[i] = f32_to_bf16(W[(size_t)(k0+i)*64 + n]);
}

// One-shot setup: W1/W2/W3 fragments, zero bfill, zero g zero-rows. 8 blocks.
__global__ __launch_bounds__(256) void setup_kernel(const float* __restrict__ W1,
                                                    const float* __restrict__ W2,
                                                    const float* __restrict__ W3,
                                                    unsigned short* __restrict__ wf1,
                                                    unsigned short* __restrict__ wf2,
                                                    unsigned short* __restrict__ wf3,
                                                    int* __restrict__ bfill,
                                                    unsigned short* __restrict__ gAz,
                                                    unsigned short* __restrict__ gBz){
  int b = blockIdx.x, t = threadIdx.x;
  if(b < 4)      wfrag_one(W1, wf1, b*256+t, 4);
  else if(b < 6) wfrag_one(W2, wf2, (b-4)*256+t, 2);
  else           wfrag_one(W3, wf3, (b-6)*256+t, 2);
  if(b < 4) bfill[b*256+t] = 0;                 // 1024 bucket counters
  if(b==4 && t<32) ((int*)gAz)[t] = 0;          // zero row (64 bf16 = 32 ints)
  if(b==5 && t<32) ((int*)gBz)[t] = 0;
}

// Scatter packed (local_dst<<17 | src) into fixed-stride bucket regions,
// LDS-presorted so global writes are dense runs. 1024 threads (16 waves).
// Bucket base is b*CCAP (compile-time stride): no hist/scan passes needed.
__global__ __launch_bounds__(1024) void scatter_kernel(const int* __restrict__ src,
                                                       const int* __restrict__ dst,
                                                       int* __restrict__ bfill,
                                                       int* __restrict__ pairs, int E){
  __shared__ int hist[NBUCK];            // counts -> reused as fill counters
  __shared__ int delta[NBUCK];           // gstart - lstart per bucket
  __shared__ int wsum[16];
  __shared__ int vals[CHUNK];            // 32KB sorted-by-bucket payloads
  __shared__ unsigned short bkt[CHUNK];  // 16KB bucket id per slot
  int t = threadIdx.x;
  int lane = t & 63, wid = t >> 6;
  int cbase = blockIdx.x*CHUNK;
  hist[t]=0;                             // NBUCK == 1024
  __syncthreads();
  // A: local histogram
  #pragma unroll
  for(int i=0;i<CHUNK;i+=1024){
    int e = cbase+i+t;
    if(e<E) atomicAdd(&hist[dst[e]>>7], 1);
  }
  __syncthreads();
  // B: block-exclusive scan (1 bucket/thread): wave shfl scan + combine
  int v = hist[t];
  int x = v;
  #pragma unroll
  for(int off=1; off<64; off<<=1){
    int y = __shfl_up(x, off, 64);
    if(lane >= off) x += y;
  }
  if(lane==63) wsum[wid]=x;
  __syncthreads();
  if(wid==0){
    int s2 = (lane<16) ? wsum[lane] : 0;
    #pragma unroll
    for(int off=1; off<16; off<<=1){
      int y = __shfl_up(s2, off, 64);
      if(lane >= off) s2 += y;
    }
    if(lane<16) wsum[lane]=s2;
  }
  __syncthreads();
  int run = (x - v) + (wid ? wsum[wid-1] : 0);      // exclusive local start
  int g = v ? atomicAdd(&bfill[t], v) : 0;          // reserve in bucket region
  hist[t]=run; delta[t]= t*CCAP + g - run;          // hist becomes fill counter
  __syncthreads();
  // C: place into LDS sorted by bucket
  #pragma unroll
  for(int i=0;i<CHUNK;i+=1024){
    int e = cbase+i+t;
    if(e<E){
      int d = dst[e];
      int b = d>>7;
      int slot = atomicAdd(&hist[b], 1);
      vals[slot] = ((d&127)<<17) | src[e];
      bkt[slot]  = (unsigned short)b;
    }
  }
  __syncthreads();
  // D: dense copy-out (addresses consecutive within each run)
  int cnt = E - cbase; if(cnt > CHUNK) cnt = CHUNK;
  for(int i=t;i<cnt;i+=1024){
    int b = bkt[i];
    pairs[delta[b] + i] = vals[i];
  }
}

// One block per bucket (128 dst nodes). LDS counting sort -> rowse {s,e},
// dinv, srcs staged in LDS -> fully-contiguous col writes.
__global__ __launch_bounds__(256) void bucket_csr_kernel(const int* __restrict__ pairs,
                                                         const int* __restrict__ bfill,
                                                         int2* __restrict__ rowse,
                                                         float* __restrict__ dinv,
                                                         int* __restrict__ col,
                                                         int N){
  __shared__ int hist[128];
  __shared__ int pref[128];
  __shared__ int fill[128];
  __shared__ int srcs[CCAP];
  int b = blockIdx.x, t = threadIdx.x;
  int s0 = b*CCAP;
  int cnt = bfill[b]; if(cnt > CCAP) cnt = CCAP;   // unreachable guard
  if(t<128) hist[t]=0;
  __syncthreads();
  int v[CCAP/256];
  #pragma unroll
  for(int i=0;i<CCAP/256;i++){
    int idx = i*256 + t;
    if(idx<cnt){ v[i]=pairs[s0+idx]; atomicAdd(&hist[v[i]>>17], 1); }
  }
  __syncthreads();
  if(t<128) pref[t]=hist[t];
  __syncthreads();
  for(int off=1; off<128; off<<=1){
    int x=0;
    if(t<128 && t>=off) x=pref[t-off];
    __syncthreads();
    if(t<128) pref[t]+=x;
    __syncthreads();
  }
  if(t<128){
    int ex = pref[t]-hist[t];                 // exclusive prefix
    fill[t]=ex;
    int node = b*128 + t;
    if(node<N){
      rowse[node] = make_int2(s0+ex, s0+ex+hist[t]);
      dinv[node] = rsqrtf((float)(hist[t]+1)); // +1 self loop
    }
  }
  __syncthreads();
  #pragma unroll
  for(int i=0;i<CCAP/256;i++){
    int idx = i*256 + t;
    if(idx<cnt){
      int ld = v[i]>>17;
      int pos = atomicAdd(&fill[ld], 1);
      srcs[pos] = v[i] & 0x1FFFF;
    }
  }
  __syncthreads();
  for(int i=t;i<cnt;i+=256) col[s0+i]=srcs[i];   // contiguous
}

// g[n,:] = bf16( dinv[n] * (x[n,:128] @ W1[128,64]) ) via MFMA 16x16x32 bf16.
// Block = 64 rows (4 waves x 16 rows), 16 MFMAs/wave (4 ksteps x 4 nblocks).
// A-frags from global (lane l: row l&15, k-octet 8*(l>>4)); B-frags from LDS.
__global__ __launch_bounds__(256) void lin_mfma_kernel(const float* __restrict__ x,
                                                       const unsigned short* __restrict__ wf,
                                                       const float* __restrict__ dinv,
                                                       unsigned short* __restrict__ g,
                                                       int N){
  __shared__ __align__(16) unsigned short wl[4*4*64*8];   // 16KB
  int t = threadIdx.x, wave = t>>6, lane = t&63;
  #pragma unroll
  for(int idx=t; idx<1024; idx+=256)
    ((v4f*)wl)[idx] = ((const v4f*)wf)[idx];              // 16B per entry
  __syncthreads();
  int row = blockIdx.x*64 + wave*16 + (lane&15);
  int arow = row < N ? row : N-1;
  const float* xr = x + (size_t)arow*128 + 8*(lane>>4);
  f32x4 acc0={0.f,0.f,0.f,0.f}, acc1=acc0, acc2=acc0, acc3=acc0;
  #pragma unroll
  for(int ks=0; ks<4; ks++){
    v4f a0 = *(const v4f*)(xr + ks*32);
    v4f a1 = *(const v4f*)(xr + ks*32 + 4);
    short8 af;
    af[0]=(short)f32_to_bf16(a0.x); af[1]=(short)f32_to_bf16(a0.y);
    af[2]=(short)f32_to_bf16(a0.z); af[3]=(short)f32_to_bf16(a0.w);
    af[4]=(short)f32_to_bf16(a1.x); af[5]=(short)f32_to_bf16(a1.y);
    af[6]=(short)f32_to_bf16(a1.z); af[7]=(short)f32_to_bf16(a1.w);
    const short8* wb = ((const short8*)wl) + ks*256 + lane;
    acc0 = __builtin_amdgcn_mfma_f32_16x16x32_bf16(af, wb[0],   acc0, 0, 0, 0);
    acc1 = __builtin_amdgcn_mfma_f32_16x16x32_bf16(af, wb[64],  acc1, 0, 0, 0);
    acc2 = __builtin_amdgcn_mfma_f32_16x16x32_bf16(af, wb[128], acc2, 0, 0, 0);
    acc3 = __builtin_amdgcn_mfma_f32_16x16x32_bf16(af, wb[192], acc3, 0, 0, 0);
  }
  // C layout (m89-verified): col = lane&15, row = (lane>>4)*4 + j.
  int rbase = blockIdx.x*64 + wave*16 + (lane>>4)*4;
  int c = lane & 15;
  #pragma unroll
  for(int j=0;j<4;j++){
    int r = rbase + j;
    if(r < N){
      float dv = dinv[r];
      unsigned short* go = g + (size_t)r*64 + c;
      go[0]  = f32_to_bf16(dv*acc0[j]);
      go[16] = f32_to_bf16(dv*acc1[j]);
      go[32] = f32_to_bf16(dv*acc2[j]);
      go[48] = f32_to_bf16(dv*acc3[j]);
    }
  }
}

// Gather for 4-nodes-per-wave layout over bf16 g rows (128B each):
// lane = 16*q + l; group q handles node n, lane carries features [4l,4l+4).
// 4-granular early break (group-uniform); OOB slots clamp to zeroed row
// g[ZR]; v4f vector accumulate -> v_pk_add_f32. (R18 form — R19's 16-deep
// batch regressed: single drain point, no consume/latency overlap.)
__device__ __forceinline__ v4f gather_row4(const unsigned short* __restrict__ g,
                                           const int* __restrict__ col,
                                           int n, int s, int e, int l, int ZR){
  v4f acc = bf16x4_to_f32(*(const v4u16*)&g[(size_t)n*64 + l*4]);   // self
  for(int i = s; i < e; i += 16){
    int rem = e - i;                               // group-uniform
    int myc = (l < rem) ? col[i + l] : ZR;
    #pragma unroll
    for(int j0 = 0; j0 < 16; j0 += 4){
      int c0 = __shfl(myc, j0+0, 16);
      int c1 = __shfl(myc, j0+1, 16);
      int c2 = __shfl(myc, j0+2, 16);
      int c3 = __shfl(myc, j0+3, 16);
      v4f x0 = bf16x4_to_f32(*(const v4u16*)&g[(size_t)c0*64 + l*4]);
      v4f x1 = bf16x4_to_f32(*(const v4u16*)&g[(size_t)c1*64 + l*4]);
      v4f x2 = bf16x4_to_f32(*(const v4u16*)&g[(size_t)c2*64 + l*4]);
      v4f x3 = bf16x4_to_f32(*(const v4u16*)&g[(size_t)c3*64 + l*4]);
      acc = acc + ((x0 + x1) + (x2 + x3));         // pk_add; same association
      if(j0+4 >= rem) break;                       // group-uniform early out
    }
  }
  return acc;
}

// Fused agg + next-layer linear. h = relu(dinv*gather + b) -> bf16 rows in
// LDS (144B pitch), then h[16x64] @ W[64x64] via 8 MFMAs (2/wave):
// wave = output col-block nb; A-frag: lane l reads row l&15, k-octet
// 8*(l>>4) (ds_read_b128, 16B-aligned, bank-stride 4 -> 2-way free).
__global__ __launch_bounds__(256) void agg_lin_kernel(const unsigned short* __restrict__ g,
                                                      const int2* __restrict__ rowse,
                                                      const int* __restrict__ col,
                                                      const float* __restrict__ dinv,
                                                      const float* __restrict__ bias,
                                                      const unsigned short* __restrict__ wf,
                                                      unsigned short* __restrict__ g2,
                                                      int N){
  __shared__ __align__(16) unsigned short hsh[16*72];     // 2.25KB padded bf16 h
  __shared__ __align__(16) unsigned short wl[2*4*64*8];   // 8KB W frags
  int t = threadIdx.x, wave = t>>6, lane = t&63;
  int l = lane & 15, q = lane >> 4;
  // stage W frags once per block: 512 x 16B, coalesced
  #pragma unroll
  for(int idx = t; idx < 512; idx += 256)
    ((v4f*)wl)[idx] = ((const v4f*)wf)[idx];
  int base = blockIdx.x*16;
  int n = base + wave*4 + q;
  bool valid = n < N;
  int nn = valid ? n : (N-1);
  int2 se = rowse[nn];
  v4f acc = gather_row4(g, col, nn, se.x, se.y, l, N);
  float dv = dinv[nn];
  v4f bs = *(const v4f*)&bias[l*4];
  v4u16 hb;
  hb.x = f32_to_bf16(fmaxf(fmaf(dv, acc.x, bs.x), 0.f));
  hb.y = f32_to_bf16(fmaxf(fmaf(dv, acc.y, bs.y), 0.f));
  hb.z = f32_to_bf16(fmaxf(fmaf(dv, acc.z, bs.z), 0.f));
  hb.w = f32_to_bf16(fmaxf(fmaf(dv, acc.w, bs.w), 0.f));
  *(v4u16*)&hsh[(wave*4+q)*72 + l*4] = hb;
  __syncthreads();
  // ---- h @ W via MFMA; this wave handles col-block nb = wave ----
  short8 a0 = *(const short8*)&hsh[(lane&15)*72 +      8*(lane>>4)];
  short8 a1 = *(const short8*)&hsh[(lane&15)*72 + 32 + 8*(lane>>4)];
  const short8* wb = ((const short8*)wl) + wave*64 + lane;
  f32x4 oc = {0.f,0.f,0.f,0.f};
  oc = __builtin_amdgcn_mfma_f32_16x16x32_bf16(a0, wb[0],   oc, 0, 0, 0);
  oc = __builtin_amdgcn_mfma_f32_16x16x32_bf16(a1, wb[256], oc, 0, 0, 0);
  // C layout: col = lane&15, row = (lane>>4)*4 + j
  int c  = wave*16 + (lane&15);
  int r0 = base + (lane>>4)*4;
  #pragma unroll
  for(int j=0;j<4;j++){
    int r = r0 + j;
    if(r < N)
      g2[(size_t)r*64 + c] = f32_to_bf16(dinv[r]*oc[j]);
  }
}

// Layer-3 agg with fused FC + log_softmax epilogue: never materializes h3.
__global__ __launch_bounds__(256) void agg_final_kernel(const unsigned short* __restrict__ g,
                                                        const int2* __restrict__ rowse,
                                                        const int* __restrict__ col,
                                                        const float* __restrict__ dinv,
                                                        const float* __restrict__ bias,
                                                        const float* __restrict__ Wfc,
                                                        const float* __restrict__ bfc,
                                                        float* __restrict__ out, int N){
  int t = threadIdx.x, wave = t>>6, lane = t&63;
  int l = lane & 15, q = lane >> 4;
  int n = blockIdx.x*16 + wave*4 + q;
  bool valid = n < N;
  if(!valid) n = N-1;
  int2 se = rowse[n];
  v4f acc = gather_row4(g, col, n, se.x, se.y, l, N);
  float dv = dinv[n];
  v4f bs = *(const v4f*)&bias[l*4];
  v4f hv;
  hv.x = fmaxf(fmaf(dv, acc.x, bs.x), 0.f);
  hv.y = fmaxf(fmaf(dv, acc.y, bs.y), 0.f);
  hv.z = fmaxf(fmaf(dv, acc.z, bs.z), 0.f);
  hv.w = fmaxf(fmaf(dv, acc.w, bs.w), 0.f);
  // Wfc row-major [64][2]: lane l covers features 4l..4l+3 -> 8 floats at 8l.
  v4f wa = *(const v4f*)&Wfc[l*8];
  v4f wb = *(const v4f*)&Wfc[l*8+4];
  float p0 = hv.x*wa.x + hv.y*wa.z + hv.z*wb.x + hv.w*wb.z;
  float p1 = hv.x*wa.y + hv.y*wa.w + hv.z*wb.y + hv.w*wb.w;
  for(int off=8; off; off>>=1){
    p0 += __shfl_down(p0, off, 16);
    p1 += __shfl_down(p1, off, 16);
  }
  if(valid && l==0){
    float l0 = p0 + bfc[0], l1 = p1 + bfc[1];
    float m  = fmaxf(l0, l1);
    float lse = m + logf(expf(l0-m) + expf(l1-m));
    out[(size_t)n*2+0] = l0 - lse;
    out[(size_t)n*2+1] = l1 - lse;
  }
}

extern "C" void kernel_launch(void* const* d_in, const int* in_sizes, int n_in,
                              void* d_out, int out_size, void* d_ws, size_t ws_size,
                              hipStream_t stream) {
  (void)n_in; (void)out_size; (void)ws_size;
  const float* x   = (const float*)d_in[0];
  const int*   ei  = (const int*)  d_in[1];
  const float* W1  = (const float*)d_in[2];
  const float* b1  = (const float*)d_in[3];
  const float* W2  = (const float*)d_in[4];
  const float* b2  = (const float*)d_in[5];
  const float* W3  = (const float*)d_in[6];
  const float* b3  = (const float*)d_in[7];
  const float* Wfc = (const float*)d_in[8];
  const float* bfc = (const float*)d_in[9];
  float* out = (float*)d_out;

  const int N = in_sizes[0] / 128;   // 100000
  const int E = in_sizes[1] / 2;     // 1600000
  const int* src = ei;
  const int* dst = ei + E;
  const int NB = (N + 127) / 128;    // 782 buckets

  // ---- workspace carve ----
  char* w = (char*)d_ws;
  int*   bfill   = (int*)  w; w += alignup((size_t)NBUCK*4);
  int*   pairs   = (int*)  w; w += alignup((size_t)NBUCK*CCAP*4);   // 14.7MB strided
  int2*  rowse   = (int2*) w; w += alignup((size_t)N*8);
  float* dinv    = (float*)w; w += alignup((size_t)N*4);
  int*   col     = (int*)  w; w += alignup((size_t)NBUCK*CCAP*4);   // 14.7MB strided
  unsigned short* gA = (unsigned short*)w; w += alignup((size_t)(N+1)*64*2); // bf16 (+zero row)
  unsigned short* gB = (unsigned short*)w; w += alignup((size_t)(N+1)*64*2); // bf16 (+zero row)
  unsigned short* wf1 = (unsigned short*)w; w += alignup((size_t)4*4*64*8*2); // W1 frags 16KB
  unsigned short* wf2 = (unsigned short*)w; w += alignup((size_t)2*4*64*8*2); // W2 frags 8KB
  unsigned short* wf3 = (unsigned short*)w; w += alignup((size_t)2*4*64*8*2); // W3 frags 8KB

  const int nblkE   = (E + CHUNK - 1) / CHUNK;   // 196
  const int nblkLin = (N + 63) / 64;             // 64 rows per MFMA block
  const int nblkAgg = (N + 15) / 16;             // 4 nodes/wave, 4 waves/blk

  // ---- setup (one kernel): W frags + bfill zero + g zero-rows ----
  setup_kernel<<<8, 256, 0, stream>>>(W1, W2, W3, wf1, wf2, wf3, bfill,
                                      gA + (size_t)N*64, gB + (size_t)N*64);
  // ---- CSR build: scatter into fixed-stride buckets, then per-bucket sort ----
  scatter_kernel<<<nblkE, 1024, 0, stream>>>(src, dst, bfill, pairs, E);
  bucket_csr_kernel<<<NB, 256, 0, stream>>>(pairs, bfill, rowse, dinv, col, N);

  // ---- layer 1 linear via MFMA: x[N,128] -> gA ----
  lin_mfma_kernel<<<nblkLin, 256, 0, stream>>>(x, wf1, dinv, gA, N);
  // ---- agg1 + lin2 fused (MFMA epilogue): gA -> gB ----
  agg_lin_kernel<<<nblkAgg, 256, 0, stream>>>(gA, rowse, col, dinv, b1, wf2, gB, N);
  // ---- agg2 + lin3 fused (MFMA epilogue): gB -> gA ----
  agg_lin_kernel<<<nblkAgg, 256, 0, stream>>>(gB, rowse, col, dinv, b2, wf3, gA, N);
  // ---- agg3 + FC + log_softmax (fused): gA -> out ----
  agg_final_kernel<<<nblkAgg, 256, 0, stream>>>(gA, rowse, col, dinv, b3,
                                                Wfc, bfc, out, N);
}